// Round 7
// baseline (30.558 us; speedup 1.0000x reference)
//
#include <hip/hip_runtime.h>

// VQ codebook search via bf16 MFMA — coalesced-I/O version.
// latents: [32, 64, 64, 64] = [b, d, h, w] fp32
// emb:     [512, 64] fp32
// out:     8388608 floats quantized (b,d,h,w) + 1 float vq_loss
//
// score'[n,k] = 16 - 2 x_n.e_k   (e2 term dropped for argmin: |e2| <= 64/512^2
//   = 2.4e-4, below accepted bf16 score noise; re-added exactly for the loss).
// MFMA 16x16x32: A = bf16(-2E) in VGPRs (wave w owns codes [w*64,w*64+64)),
// B = bf16(X) from chunk-XOR-swizzled LDS, C-init = 16.0 => D = score' > 0.
// argmin key = (float_bits(score') & ~511) | code  (positive => bit-monotone).
// loss identity: ||q-x||^2 = ||x||^2 + (score'-16) + e2[ind].
//
// I/O: latents staged hw-major via global_load_lds dwordx4 (1KB/instr linear
// into fp32 [d][px] LDS); output stored d-major float4 (512B/instr) after a
// 4x4 register transpose of per-row float4 gathers.
//
// ws layout (floats): [0..1024) per-block loss partials; [1024..1536) e2;
//   ws+1536: ebf2 = bf16(-2E) as [2 halves][512 codes][32 d], 64KB.

typedef short short8v __attribute__((ext_vector_type(8)));
typedef float f32x4   __attribute__((ext_vector_type(4)));

constexpr int K = 512;
constexpr int D = 64;
constexpr int HW = 4096;
constexpr int NPIX = 32 * HW;
constexpr long long NELEM = (long long)NPIX * D;
constexpr int PXT = 128;                 // pixels per block (one tile)
constexpr int NBLK = NPIX / PXT;         // 1024 blocks

__device__ inline unsigned short f2bf(float f) {   // RNE float->bf16 bits
    unsigned int u = __builtin_bit_cast(unsigned int, f);
    u += 0x7fffu + ((u >> 16) & 1u);
    return (unsigned short)(u >> 16);
}

__device__ inline unsigned umin32(unsigned a, unsigned b) { return a < b ? a : b; }

// ---- prep: e2[k] = ||e_k||^2 fp32; ebf2[h][k][j] = bf16(-2*emb[k][h*32+j]).
__global__ __launch_bounds__(256) void vq_prep(const float* __restrict__ emb,
                                               float* __restrict__ e2,
                                               unsigned short* __restrict__ ebf2) {
    int tid = blockIdx.x * 256 + threadIdx.x;    // 0..8191 = k*4 + quad (16 d's each)
    int k = tid >> 2, quad = tid & 3;
    const float4* src = reinterpret_cast<const float4*>(emb + k * D + quad * 16);
    unsigned int pk[8];
    float s = 0.f;
    #pragma unroll
    for (int i = 0; i < 4; ++i) {
        float4 v = src[i];
        s = fmaf(v.x, v.x, fmaf(v.y, v.y, fmaf(v.z, v.z, fmaf(v.w, v.w, s))));
        pk[2*i]   = (unsigned int)f2bf(-2.f * v.x) | ((unsigned int)f2bf(-2.f * v.y) << 16);
        pk[2*i+1] = (unsigned int)f2bf(-2.f * v.z) | ((unsigned int)f2bf(-2.f * v.w) << 16);
    }
    s += __shfl_xor(s, 1, 64);                   // reduce over the 4 quads of row k
    s += __shfl_xor(s, 2, 64);
    if (quad == 0) e2[k] = s;
    int h = quad >> 1, jb = (quad & 1) * 16;
    unsigned int* dst = reinterpret_cast<unsigned int*>(ebf2 + h * (K * 32) + k * 32 + jb);
    *reinterpret_cast<uint4*>(dst)     = uint4{pk[0], pk[1], pk[2], pk[3]};
    *reinterpret_cast<uint4*>(dst + 4) = uint4{pk[4], pk[5], pk[6], pk[7]};
}

// ---- main: 1024 blocks x 512 threads; 128 px/block; codes split across 8 waves.
__global__ __launch_bounds__(512, 6) void vq_main(const float* __restrict__ latents,
                                                  const float* __restrict__ emb,
                                                  const float* __restrict__ e2,
                                                  const unsigned short* __restrict__ ebf2,
                                                  float* __restrict__ out,
                                                  float* __restrict__ partials) {
    __shared__ float          xs[D][PXT];        // 32KB fp32 d-major (DMA dest, linear)
    __shared__ unsigned short xbf[PXT * D];      // 16KB bf16 px-major, chunk-XOR swizzled
    __shared__ unsigned int   kred[8][PXT];      // 4KB per-wave best keys
    __shared__ unsigned short inds[PXT];         // 256B chosen codes
    __shared__ float          wsum[8], ssum[2];

    const int t    = threadIdx.x;
    const int lane = t & 63, w = t >> 6;         // 8 waves
    const int r15  = lane & 15, g = lane >> 4;
    const int tile = blockIdx.x;
    const int b    = tile >> 5, hw0 = (tile & 31) * PXT;
    const int p4   = t & 31,  dh = t >> 5;       // pack/epilogue mapping
    const int px0  = p4 * 4,  d0 = dh * 4;

    // ---- stage: global->LDS DMA, hw-major float4 per lane, 1KB linear/instr.
    // Wave w fills d-rows [8w, 8w+8): instr i covers rows 8w+2i (lanes 0-31)
    // and 8w+2i+1 (lanes 32-63).
    {
        const float* base = latents + (size_t)b * D * HW + hw0;
        char* ldst = reinterpret_cast<char*>(&xs[0][0]);
        #pragma unroll
        for (int i = 0; i < 4; ++i) {
            int drow = w * 8 + i * 2 + (lane >> 5);
            const float* src = base + (size_t)drow * HW + (lane & 31) * 4;
            __builtin_amdgcn_global_load_lds(
                (const __attribute__((address_space(1))) unsigned int*)src,
                (__attribute__((address_space(3))) unsigned int*)(ldst + (w * 8 + i * 2) * 512),
                16, 0, 0);
        }
    }

    // ---- this wave's codebook slice -> VGPRs (L2/L3-resident).
    short8v A0[4], A1[4];
    const char* eb = reinterpret_cast<const char*>(ebf2);
    #pragma unroll
    for (int tt = 0; tt < 4; ++tt) {
        int code = w * 64 + tt * 16 + r15;
        A0[tt] = *reinterpret_cast<const short8v*>(eb + (size_t)code * 64 + g * 16);
        A1[tt] = *reinterpret_cast<const short8v*>(eb + (size_t)(K * 64) + (size_t)code * 64 + g * 16);
    }
    __syncthreads();                             // DMA landed; xs visible

    // ---- pack: read [d][px] b128 (4 rows x 4 px), 4x4 transpose, f2bf,
    // write px-major with 16B-chunk XOR swizzle  c ^= (px>>1)&7.
    f32x4 r0 = *reinterpret_cast<const f32x4*>(&xs[d0 + 0][px0]);
    f32x4 r1 = *reinterpret_cast<const f32x4*>(&xs[d0 + 1][px0]);
    f32x4 r2 = *reinterpret_cast<const f32x4*>(&xs[d0 + 2][px0]);
    f32x4 r3 = *reinterpret_cast<const f32x4*>(&xs[d0 + 3][px0]);
    char* xc = reinterpret_cast<char*>(xbf);
    #pragma unroll
    for (int j = 0; j < 4; ++j) {
        int px = px0 + j;
        unsigned lo = (unsigned)f2bf(r0[j]) | ((unsigned)f2bf(r1[j]) << 16);
        unsigned hi = (unsigned)f2bf(r2[j]) | ((unsigned)f2bf(r3[j]) << 16);
        int byte = px * 128 + (((dh >> 1) ^ ((px >> 1) & 7)) << 4) + (dh & 1) * 8;
        *reinterpret_cast<uint2*>(xc + byte) = uint2{lo, hi};
    }
    float x2 = 0.f;
    #pragma unroll
    for (int j = 0; j < 4; ++j) {
        x2 = fmaf(r0[j], r0[j], x2); x2 = fmaf(r1[j], r1[j], x2);
        x2 = fmaf(r2[j], r2[j], x2); x2 = fmaf(r3[j], r3[j], x2);
    }
    #pragma unroll
    for (int off = 32; off > 0; off >>= 1) x2 += __shfl_down(x2, off, 64);
    if (lane == 0) wsum[w] = x2;
    __syncthreads();                             // xbf visible

    // ---- k-loop: wave scans all 8 pixel-tiles against its 64 codes.
    const unsigned lc = (unsigned)(g * 4);
    #pragma unroll 2
    for (int pt = 0; pt < 8; ++pt) {
        const int P = pt * 16 + r15;
        const int sP = (P >> 1) & 7;
        short8v b0 = *reinterpret_cast<const short8v*>(xc + P * 128 + ((g ^ sP) << 4));
        short8v b1 = *reinterpret_cast<const short8v*>(xc + P * 128 + (((g + 4) ^ sP) << 4));
        unsigned best = 0xFFFFFFFFu;
        #pragma unroll
        for (int tt = 0; tt < 4; ++tt) {
            f32x4 c = {16.f, 16.f, 16.f, 16.f};  // uniform bias => D = score' > 0
            c = __builtin_amdgcn_mfma_f32_16x16x32_bf16(A0[tt], b0, c, 0, 0, 0);
            c = __builtin_amdgcn_mfma_f32_16x16x32_bf16(A1[tt], b1, c, 0, 0, 0);
            #pragma unroll
            for (int el = 0; el < 4; ++el) {
                unsigned u = __builtin_bit_cast(unsigned, c[el]);
                best = umin32(best, (u & 0xFFFFFE00u) | (lc + (unsigned)(tt * 16 + el)));
            }
        }
        #pragma unroll
        for (int off = 16; off < 64; off <<= 1)  // cross-g reduce (same pixel P)
            best = umin32(best, (unsigned)__shfl_xor((int)best, off, 64));
        if (g == 0) kred[w][P] = best + ((unsigned)w << 6);  // globalize code bits
    }
    __syncthreads();

    // ---- cross-wave argmin + loss score part (+ exact e2 re-add).
    if (t < PXT) {
        unsigned key = kred[0][t];
        #pragma unroll
        for (int wv = 1; wv < 8; ++wv) key = umin32(key, kred[wv][t]);
        int ind = (int)(key & 511u);
        inds[t] = (unsigned short)ind;
        float sq = __builtin_bit_cast(float, key & 0xFFFFFE00u) - 16.0f + e2[ind];
        #pragma unroll
        for (int off = 32; off > 0; off >>= 1) sq += __shfl_down(sq, off, 64);
        if (lane == 0) ssum[t >> 6] = sq;
    }
    __syncthreads();                             // inds visible

    // ---- epilogue: gather 4 code rows (b128, L1-reused), 4x4 transpose,
    // store d-major float4 (512B contiguous per instr).
    unsigned long long iv = *reinterpret_cast<const unsigned long long*>(&inds[px0]);
    f32x4 q0 = *reinterpret_cast<const f32x4*>(emb + ((iv      ) & 511u) * D + d0);
    f32x4 q1 = *reinterpret_cast<const f32x4*>(emb + ((iv >> 16) & 511u) * D + d0);
    f32x4 q2 = *reinterpret_cast<const f32x4*>(emb + ((iv >> 32) & 511u) * D + d0);
    f32x4 q3 = *reinterpret_cast<const f32x4*>(emb + ((iv >> 48) & 511u) * D + d0);
    float* og = out + ((size_t)b * D + d0) * HW + hw0 + px0;
    #pragma unroll
    for (int i = 0; i < 4; ++i) {
        f32x4 o = {q0[i], q1[i], q2[i], q3[i]};
        *reinterpret_cast<f32x4*>(og + (size_t)i * HW) = o;
    }

    if (t == 0) {
        float s = ssum[0] + ssum[1];
        #pragma unroll
        for (int i = 0; i < 8; ++i) s += wsum[i];
        partials[blockIdx.x] = s;                // sum_px (||x||^2 + best score)
    }
}

__global__ __launch_bounds__(1024) void vq_finalize(const float* __restrict__ partials,
                                                    float* __restrict__ out_loss) {
    int t = threadIdx.x;
    float v = partials[t];                       // 1024 partials, one block
    #pragma unroll
    for (int off = 32; off > 0; off >>= 1) v += __shfl_down(v, off, 64);
    __shared__ float s16[16];
    if ((t & 63) == 0) s16[t >> 6] = v;
    __syncthreads();
    if (t == 0) {
        float tot = 0.f;
        #pragma unroll
        for (int i = 0; i < 16; ++i) tot += s16[i];
        out_loss[0] = 1.25f * tot / (float)NELEM;   // beta*commit + embed (equal values)
    }
}

extern "C" void kernel_launch(void* const* d_in, const int* in_sizes, int n_in,
                              void* d_out, int out_size, void* d_ws, size_t ws_size,
                              hipStream_t stream) {
    const float* latents = (const float*)d_in[0];
    const float* emb     = (const float*)d_in[1];
    float* out = (float*)d_out;
    float* ws  = (float*)d_ws;

    float*          part = ws;                               // [0..1024)
    float*          e2   = ws + 1024;                        // [1024..1536)
    unsigned short* ebf2 = (unsigned short*)(ws + 1536);     // 64KB

    vq_prep<<<32, 256, 0, stream>>>(emb, e2, ebf2);
    vq_main<<<NBLK, 512, 0, stream>>>(latents, emb, e2, ebf2, out, part);
    vq_finalize<<<1, 1024, 0, stream>>>(part, out + NELEM);
}